// Round 1
// baseline (2455.972 us; speedup 1.0000x reference)
//
#include <hip/hip_runtime.h>
#include <hip/hip_bf16.h>
#include <math.h>

// Problem constants
#define PN0 131072
#define PN1 16384
#define PN2 4096
#define PK  8
#define PD  256
#define PH  256

// ---------------- prep kernels ----------------
__global__ __launch_bounds__(256) void concat_rows_kernel(
    float* __restrict__ dst, const float* __restrict__ A,
    const float* __restrict__ B, int rows) {
  int gid = blockIdx.x * 256 + threadIdx.x;
  if (gid >= rows * 128) return;
  int r = gid >> 7, q = gid & 127;
  float4 v = (q < 64) ? ((const float4*)(A + (size_t)r * 256))[q]
                      : ((const float4*)(B + (size_t)r * 256))[q - 64];
  ((float4*)(dst + (size_t)r * 512))[q] = v;
}

__global__ __launch_bounds__(256) void add_bias_kernel(
    float* __restrict__ dst, const float* __restrict__ a,
    const float* __restrict__ b, int n) {
  int i = blockIdx.x * 256 + threadIdx.x;
  if (i < n) dst[i] = a[i] + b[i];
}

__device__ __forceinline__ float sigf(float x) { return 1.f / (1.f + expf(-x)); }

// ---------------- LSTM step: z = [x_t, h] @ Wcat^T + bcat; gates; c,h update --------
// Grid: (M/64, 4). Block 256. Per block: 64 rows x 64 hidden-cols x 4 gates.
__global__ __launch_bounds__(256) void lstm_step_kernel(
    const float* __restrict__ gsrc,   // gather source rows (stride 256)
    const int*   __restrict__ idx,    // (M, 8) int32
    int t,
    const float* h_prev, const float* c_prev,
    const float* __restrict__ Wcat,   // (1024 x 512)
    const float* __restrict__ bcat,   // (1024)
    float* h_out, float* c_out, int first)
{
  __shared__ float Xs[64][36];        // padded rows
  __shared__ float Ws[4][32][64];     // [gate][k][col]

  const int tid = threadIdx.x;
  const int m0  = blockIdx.x * 64;
  const int hc0 = blockIdx.y * 64;
  const int ty = tid >> 4, tx = tid & 15;
  const int r0 = ty * 4, c0 = tx * 4;

  float acc[4][4][4];
#pragma unroll
  for (int g = 0; g < 4; ++g)
#pragma unroll
    for (int i = 0; i < 4; ++i)
#pragma unroll
      for (int j = 0; j < 4; ++j) acc[g][i][j] = 0.f;

  // X loader mapping: 4 threads per row, 8 floats each
  const int lr = tid >> 2;
  const int lk = (tid & 3) * 8;
  const int gm = m0 + lr;
  const int grow = idx[(size_t)gm * PK + t];
  const float* xrowA = gsrc + (size_t)grow * 256;     // k in [0,256)
  const float* xrowB = h_prev + (size_t)gm * 256;     // k in [256,512)

  // W loader mapping: one (gate,col) per thread, 32 k's
  const int wg = tid >> 6;
  const int wc = tid & 63;
  const float* wrow = Wcat + (size_t)(wg * 256 + hc0 + wc) * 512;

  const int nchunk = first ? 8 : 16;   // if h==0, skip the W_hh half entirely
  for (int kc = 0; kc < nchunk; ++kc) {
    const int k0 = kc * 32;
    __syncthreads();
    { // stage X (64 rows x 32 k)
      const float* src = (k0 < 256) ? (xrowA + k0 + lk) : (xrowB + (k0 - 256) + lk);
      float4 a = ((const float4*)src)[0];
      float4 b = ((const float4*)src)[1];
      *(float4*)&Xs[lr][lk]     = a;
      *(float4*)&Xs[lr][lk + 4] = b;
    }
    { // stage W (4 gates x 64 cols x 32 k), store k-major
#pragma unroll
      for (int u = 0; u < 8; ++u) {
        float4 w = *(const float4*)(wrow + k0 + u * 4);
        Ws[wg][u * 4 + 0][wc] = w.x;
        Ws[wg][u * 4 + 1][wc] = w.y;
        Ws[wg][u * 4 + 2][wc] = w.z;
        Ws[wg][u * 4 + 3][wc] = w.w;
      }
    }
    __syncthreads();
#pragma unroll 4
    for (int k = 0; k < 32; ++k) {
      float x0 = Xs[r0 + 0][k], x1 = Xs[r0 + 1][k];
      float x2 = Xs[r0 + 2][k], x3 = Xs[r0 + 3][k];
#pragma unroll
      for (int g = 0; g < 4; ++g) {
        float4 w = *(const float4*)&Ws[g][k][c0];
        acc[g][0][0] += x0 * w.x; acc[g][0][1] += x0 * w.y; acc[g][0][2] += x0 * w.z; acc[g][0][3] += x0 * w.w;
        acc[g][1][0] += x1 * w.x; acc[g][1][1] += x1 * w.y; acc[g][1][2] += x1 * w.z; acc[g][1][3] += x1 * w.w;
        acc[g][2][0] += x2 * w.x; acc[g][2][1] += x2 * w.y; acc[g][2][2] += x2 * w.z; acc[g][2][3] += x2 * w.w;
        acc[g][3][0] += x3 * w.x; acc[g][3][1] += x3 * w.y; acc[g][3][2] += x3 * w.z; acc[g][3][3] += x3 * w.w;
      }
    }
  }

  // epilogue: gates -> c,h
#pragma unroll
  for (int i = 0; i < 4; ++i) {
    const int m = m0 + r0 + i;
    const size_t base = (size_t)m * 256 + hc0 + c0;
    float co[4];
    if (first) { co[0] = co[1] = co[2] = co[3] = 0.f; }
    else {
      float4 cv = *(const float4*)&c_prev[base];
      co[0] = cv.x; co[1] = cv.y; co[2] = cv.z; co[3] = cv.w;
    }
    float hn[4], cn[4];
#pragma unroll
    for (int j = 0; j < 4; ++j) {
      const int hc = hc0 + c0 + j;
      float zi = acc[0][i][j] + bcat[hc];
      float zf = acc[1][i][j] + bcat[256 + hc];
      float zg = acc[2][i][j] + bcat[512 + hc];
      float zo = acc[3][i][j] + bcat[768 + hc];
      float cnew = sigf(zf) * co[j] + sigf(zi) * tanhf(zg);
      float hnew = sigf(zo) * tanhf(cnew);
      cn[j] = cnew; hn[j] = hnew;
    }
    *(float4*)&c_out[base] = make_float4(cn[0], cn[1], cn[2], cn[3]);
    *(float4*)&h_out[base] = make_float4(hn[0], hn[1], hn[2], hn[3]);
  }
}

// ---------------- generic combine GEMM: out = act(X @ W^T + bias) ----------------
// X rows: [src1[m] (256) | src2[m] (256 if src2)]; W: (256 x Ktot) row-major.
__global__ __launch_bounds__(256) void gemm_combine_kernel(
    const float* __restrict__ src1, const float* src2,
    const float* __restrict__ W, const float* __restrict__ bias,
    float* __restrict__ out, int Ktot, int do_gelu)
{
  __shared__ float Xs[64][36];
  __shared__ float Ws[32][64];

  const int tid = threadIdx.x;
  const int m0  = blockIdx.x * 64;
  const int hc0 = blockIdx.y * 64;
  const int ty = tid >> 4, tx = tid & 15;
  const int r0 = ty * 4, c0 = tx * 4;

  float acc[4][4];
#pragma unroll
  for (int i = 0; i < 4; ++i)
#pragma unroll
    for (int j = 0; j < 4; ++j) acc[i][j] = 0.f;

  const int lr = tid >> 2;
  const int lk = (tid & 3) * 8;
  const float* xrowA = src1 + (size_t)(m0 + lr) * 256;
  const float* xrowB = src2 ? src2 + (size_t)(m0 + lr) * 256 : nullptr;

  const int wn = tid >> 2;             // 0..63 output col
  const int wk = (tid & 3) * 8;
  const float* wrow = W + (size_t)(hc0 + wn) * Ktot;

  const int nchunk = Ktot / 32;
  for (int kc = 0; kc < nchunk; ++kc) {
    const int k0 = kc * 32;
    __syncthreads();
    {
      const float* src = (k0 < 256) ? (xrowA + k0 + lk) : (xrowB + (k0 - 256) + lk);
      float4 a = ((const float4*)src)[0];
      float4 b = ((const float4*)src)[1];
      *(float4*)&Xs[lr][lk]     = a;
      *(float4*)&Xs[lr][lk + 4] = b;
    }
    {
#pragma unroll
      for (int u = 0; u < 2; ++u) {
        float4 w = *(const float4*)(wrow + k0 + wk + u * 4);
        Ws[wk + u * 4 + 0][wn] = w.x;
        Ws[wk + u * 4 + 1][wn] = w.y;
        Ws[wk + u * 4 + 2][wn] = w.z;
        Ws[wk + u * 4 + 3][wn] = w.w;
      }
    }
    __syncthreads();
#pragma unroll 4
    for (int k = 0; k < 32; ++k) {
      float x0 = Xs[r0 + 0][k], x1 = Xs[r0 + 1][k];
      float x2 = Xs[r0 + 2][k], x3 = Xs[r0 + 3][k];
      float4 w = *(const float4*)&Ws[k][c0];
      acc[0][0] += x0 * w.x; acc[0][1] += x0 * w.y; acc[0][2] += x0 * w.z; acc[0][3] += x0 * w.w;
      acc[1][0] += x1 * w.x; acc[1][1] += x1 * w.y; acc[1][2] += x1 * w.z; acc[1][3] += x1 * w.w;
      acc[2][0] += x2 * w.x; acc[2][1] += x2 * w.y; acc[2][2] += x2 * w.z; acc[2][3] += x2 * w.w;
      acc[3][0] += x3 * w.x; acc[3][1] += x3 * w.y; acc[3][2] += x3 * w.z; acc[3][3] += x3 * w.w;
    }
  }

#pragma unroll
  for (int i = 0; i < 4; ++i) {
    const int m = m0 + r0 + i;
    float o[4];
#pragma unroll
    for (int j = 0; j < 4; ++j) {
      float v = acc[i][j] + bias[hc0 + c0 + j];
      if (do_gelu) v = 0.5f * v * (1.f + erff(v * 0.70710678118654752f));
      o[j] = v;
    }
    *(float4*)&out[(size_t)m * 256 + hc0 + c0] = make_float4(o[0], o[1], o[2], o[3]);
  }
}

// ---------------- layernorm (+ optional batchnorm) ----------------
__global__ __launch_bounds__(256) void ln_bn_kernel(
    const float* __restrict__ in, float* __restrict__ out,
    const float* __restrict__ g, const float* __restrict__ b,
    const float* bnm, const float* bnv, const float* bng, const float* bnb,
    int do_bn)
{
  const int row  = blockIdx.x * 4 + (threadIdx.x >> 6);
  const int lane = threadIdx.x & 63;
  const int c = lane * 4;
  float4 v = *(const float4*)(in + (size_t)row * 256 + c);
  float s = v.x + v.y + v.z + v.w;
  float q = v.x * v.x + v.y * v.y + v.z * v.z + v.w * v.w;
#pragma unroll
  for (int o = 32; o > 0; o >>= 1) { s += __shfl_xor(s, o); q += __shfl_xor(q, o); }
  const float mu = s * (1.f / 256.f);
  const float var = q * (1.f / 256.f) - mu * mu;
  const float rs = rsqrtf(var + 1e-5f);
  float vv[4] = { v.x, v.y, v.z, v.w };
  float y[4];
#pragma unroll
  for (int j = 0; j < 4; ++j) {
    float t = (vv[j] - mu) * rs * g[c + j] + b[c + j];
    if (do_bn) t = (t - bnm[c + j]) * rsqrtf(bnv[c + j] + 1e-5f) * bng[c + j] + bnb[c + j];
    y[j] = t;
  }
  *(float4*)(out + (size_t)row * 256 + c) = make_float4(y[0], y[1], y[2], y[3]);
}

// ---------------- final head: out[m] = dot(h4[m], W2) + b2 ----------------
__global__ __launch_bounds__(256) void head_kernel(
    const float* __restrict__ h4, const float* __restrict__ W2,
    const float* __restrict__ b2, float* __restrict__ out)
{
  const int row  = blockIdx.x * 4 + (threadIdx.x >> 6);
  const int lane = threadIdx.x & 63;
  float4 a = *(const float4*)(h4 + (size_t)row * 256 + lane * 4);
  float4 w = *(const float4*)(W2 + lane * 4);
  float s = a.x * w.x + a.y * w.y + a.z * w.z + a.w * w.w;
#pragma unroll
  for (int o = 32; o > 0; o >>= 1) s += __shfl_xor(s, o);
  if (lane == 0) out[row] = s + b2[0];
}

// ---------------- launch ----------------
extern "C" void kernel_launch(void* const* d_in, const int* in_sizes, int n_in,
                              void* d_out, int out_size, void* d_ws, size_t ws_size,
                              hipStream_t stream) {
  const float* h0       = (const float*)d_in[0];
  const int*   idx0     = (const int*)  d_in[1];
  const int*   idx1     = (const int*)  d_in[2];
  const float* W_ih1    = (const float*)d_in[3];
  const float* W_hh1    = (const float*)d_in[4];
  const float* b_ih1    = (const float*)d_in[5];
  const float* b_hh1    = (const float*)d_in[6];
  const float* W_self1  = (const float*)d_in[7];
  const float* W_neigh1 = (const float*)d_in[8];
  const float* b_neigh1 = (const float*)d_in[9];
  const float* W_ih2    = (const float*)d_in[10];
  const float* W_hh2    = (const float*)d_in[11];
  const float* b_ih2    = (const float*)d_in[12];
  const float* b_hh2    = (const float*)d_in[13];
  const float* W_self2  = (const float*)d_in[14];
  const float* W_neigh2 = (const float*)d_in[15];
  const float* b_neigh2 = (const float*)d_in[16];
  const float* ln_g     = (const float*)d_in[17];
  const float* ln_b     = (const float*)d_in[18];
  const float* bn_g     = (const float*)d_in[19];
  const float* bn_b     = (const float*)d_in[20];
  const float* bn_mean  = (const float*)d_in[21];
  const float* bn_var   = (const float*)d_in[22];
  const float* W1       = (const float*)d_in[23];
  const float* b1       = (const float*)d_in[24];
  const float* W2       = (const float*)d_in[25];
  const float* b2       = (const float*)d_in[26];
  float* out = (float*)d_out;

  // workspace layout (floats); total ~24.4M floats (~98 MB)
  float* ws    = (float*)d_ws;
  float* Wcat1 = ws;                       // 1024*512
  float* Wcat2 = Wcat1 + 524288;           // 1024*512
  float* Wcmb1 = Wcat2 + 524288;           // 256*512
  float* Wcmb2 = Wcmb1 + 131072;           // 256*512
  float* bcat1 = Wcmb2 + 131072;           // 1024
  float* bcat2 = bcat1 + 1024;             // 1024
  float* hping = bcat2 + 1024;             // 16384*256
  float* hpong = hping + 4194304;          // 16384*256
  float* cbuf  = hpong + 4194304;          // 16384*256
  float* sbuf  = cbuf  + 4194304;          // 16384*256
  float* h1    = sbuf  + 4194304;          // 16384*256
  float* h3    = h1    + 4194304;          // 4096*256
  float* h4    = h3    + 1048576;          // 4096*256

  // ---- prep: concat weights, sum biases ----
  concat_rows_kernel<<<512, 256, 0, stream>>>(Wcat1, W_ih1, W_hh1, 1024);
  concat_rows_kernel<<<512, 256, 0, stream>>>(Wcat2, W_ih2, W_hh2, 1024);
  concat_rows_kernel<<<128, 256, 0, stream>>>(Wcmb1, W_self1, W_neigh1, 256);
  concat_rows_kernel<<<128, 256, 0, stream>>>(Wcmb2, W_self2, W_neigh2, 256);
  add_bias_kernel<<<4, 256, 0, stream>>>(bcat1, b_ih1, b_hh1, 1024);
  add_bias_kernel<<<4, 256, 0, stream>>>(bcat2, b_ih2, b_hh2, 1024);

  // ---- layer 1 LSTM over K=8 gathered steps ----
  dim3 g1(PN1 / 64, 4);
  for (int t = 0; t < PK; ++t) {
    const float* hin = (t & 1) ? hpong : hping;
    float*      hout = (t & 1) ? hping : hpong;
    lstm_step_kernel<<<g1, 256, 0, stream>>>(h0, idx0, t, hin, cbuf, Wcat1, bcat1,
                                             hout, cbuf, t == 0);
  }
  // final h_n1 = hping (t=7 writes hping)
  gemm_combine_kernel<<<dim3(PN1 / 64, 4), 256, 0, stream>>>(h0, hping, Wcmb1, b_neigh1,
                                                             sbuf, 512, 1);
  ln_bn_kernel<<<PN1 / 4, 256, 0, stream>>>(sbuf, h1, ln_g, ln_b,
                                            nullptr, nullptr, nullptr, nullptr, 0);

  // ---- layer 2 LSTM ----
  dim3 g2(PN2 / 64, 4);
  for (int t = 0; t < PK; ++t) {
    const float* hin = (t & 1) ? hpong : hping;
    float*      hout = (t & 1) ? hping : hpong;
    lstm_step_kernel<<<g2, 256, 0, stream>>>(h1, idx1, t, hin, cbuf, Wcat2, bcat2,
                                             hout, cbuf, t == 0);
  }
  gemm_combine_kernel<<<dim3(PN2 / 64, 4), 256, 0, stream>>>(h1, hping, Wcmb2, b_neigh2,
                                                             sbuf, 512, 1);
  // LN then BN fused
  ln_bn_kernel<<<PN2 / 4, 256, 0, stream>>>(sbuf, h3, ln_g, ln_b,
                                            bn_mean, bn_var, bn_g, bn_b, 1);
  // MLP layer 1 (K=256, gelu)
  gemm_combine_kernel<<<dim3(PN2 / 64, 4), 256, 0, stream>>>(h3, nullptr, W1, b1,
                                                             h4, 256, 1);
  // head
  head_kernel<<<PN2 / 4, 256, 0, stream>>>(h4, W2, b2, out);
}

// Round 2
// 655.993 us; speedup vs baseline: 3.7439x; 3.7439x over previous
//
#include <hip/hip_runtime.h>
#include <hip/hip_bf16.h>
#include <math.h>

#define PN0 131072
#define PN1 16384
#define PN2 4096
#define PK  8

typedef __attribute__((ext_vector_type(8))) short short8;
typedef __attribute__((ext_vector_type(4))) float f32x4;

__device__ __forceinline__ unsigned pkbf2(float a, float b) {
  unsigned ua = __float_as_uint(a); ua = (ua + 0x7FFFu + ((ua >> 16) & 1u)) >> 16;
  unsigned ub = __float_as_uint(b); ub = (ub + 0x7FFFu + ((ub >> 16) & 1u)) >> 16;
  return ua | (ub << 16);
}
__device__ __forceinline__ unsigned short bf16r(float a) {
  unsigned ua = __float_as_uint(a);
  return (unsigned short)((ua + 0x7FFFu + ((ua >> 16) & 1u)) >> 16);
}
__device__ __forceinline__ float sigf(float x) { return 1.f / (1.f + __expf(-x)); }
__device__ __forceinline__ float tanh_fast(float x) { return 1.f - 2.f / (__expf(2.f * x) + 1.f); }

__device__ __forceinline__ void gload16(const void* g, void* l) {
  __builtin_amdgcn_global_load_lds(
      (const __attribute__((address_space(1))) void*)g,
      (__attribute__((address_space(3))) void*)l, 16, 0, 0);
}

// ---------------- weight pack: Wcat (1024x512) -> tiled/permuted/swizzled bf16 ----------------
// flat short index t: e=t&7, slot=(t>>3)&3, row=(t>>5)&127, kc=(t>>12)&15, tn=t>>16
__global__ __launch_bounds__(256) void pack_w_kernel(
    unsigned short* __restrict__ dst, const float* __restrict__ Wih,
    const float* __restrict__ Whh) {
  int t = blockIdx.x * 256 + threadIdx.x;      // 524288 total
  int e = t & 7, slot = (t >> 3) & 3, row = (t >> 5) & 127;
  int kc = (t >> 12) & 15, tn = t >> 16;
  int s = (row >> 1) & 3;
  int q = slot ^ s;                            // logical 8-group
  int k = kc * 32 + 16 * (e >> 2) + 4 * q + (e & 3);
  int hc = tn * 32 + ((row >> 6) << 4) + (row & 15);
  int g = (row >> 4) & 3;
  int n = g * 256 + hc;
  float v = (k < 256) ? Wih[(size_t)n * 256 + k] : Whh[(size_t)n * 256 + (k - 256)];
  dst[t] = bf16r(v);
}

__global__ __launch_bounds__(256) void concat_rows_kernel(
    float* __restrict__ dst, const float* __restrict__ A,
    const float* __restrict__ B, int rows) {
  int gid = blockIdx.x * 256 + threadIdx.x;
  if (gid >= rows * 128) return;
  int r = gid >> 7, q = gid & 127;
  float4 v = (q < 64) ? ((const float4*)(A + (size_t)r * 256))[q]
                      : ((const float4*)(B + (size_t)r * 256))[q - 64];
  ((float4*)(dst + (size_t)r * 512))[q] = v;
}

__global__ __launch_bounds__(256) void add_bias_kernel(
    float* __restrict__ dst, const float* __restrict__ a,
    const float* __restrict__ b, int n) {
  int i = blockIdx.x * 256 + threadIdx.x;
  if (i < n) dst[i] = a[i] + b[i];
}

// ---------------- MFMA LSTM step ----------------
// grid (M/128, 8); block 256 (4 waves, 2x2). Z = [x_t | h] @ packW ; gates -> c,h.
__global__ __launch_bounds__(256) void lstm_mfma_kernel(
    const float* __restrict__ gsrc,              // fp32 gather source (x rows)
    const int* __restrict__ idx, int t,
    const unsigned short* __restrict__ hb_in,    // bf16 permuted h_prev
    const unsigned short* __restrict__ packW,    // packed weights
    const float* __restrict__ bcat,              // b_ih+b_hh (1024)
    float* __restrict__ cbuf,
    unsigned short* __restrict__ hb_out,         // bf16 permuted h_out
    float* __restrict__ hf32,                    // fp32 h_out (may be null)
    int first)
{
  __shared__ short As[2][128 * 32];
  __shared__ short Bs[2][128 * 32];

  const int tid = threadIdx.x;
  const int l = tid & 63;
  const int w = tid >> 6;
  const int m0 = blockIdx.x * 128;
  const int tn = blockIdx.y;
  const int wm = w >> 1, wn = w & 1;

  // ---- staging constants ----
  const int q = (l & 3) ^ ((l >> 3) & 3);        // logical 8-elem group this lane fetches
  const int r0 = w * 32 + (l >> 2);              // LDS row (inst 0)
  const int m_a = m0 + r0;
  const int m_b = m_a + 16;
  const float* xp0 = gsrc + (size_t)idx[(size_t)m_a * PK + t] * 256 + 4 * q;
  const float* xp1 = gsrc + (size_t)idx[(size_t)m_b * PK + t] * 256 + 4 * q;
  const unsigned short* hp0 = hb_in + (size_t)m_a * 256 + 8 * q;
  const unsigned short* hp1 = hb_in + (size_t)m_b * 256 + 8 * q;
  const unsigned short* bp = packW + (size_t)tn * 65536 + (size_t)w * 1024 + (size_t)l * 8;
  const int wrX = (l & 3) * 8;                   // phys slot offset (shorts) for reg-stage writes

  f32x4 acc[4][4];
#pragma unroll
  for (int mi = 0; mi < 4; ++mi)
#pragma unroll
    for (int ni = 0; ni < 4; ++ni) acc[mi][ni] = (f32x4)(0.f);

  auto STAGE = [&](int buf, int kc) {
    short* Ad = &As[buf][0];
    short* Bd = &Bs[buf][0];
    // B: linear copy of the prepacked 8KB tile (this wave's 2KB)
    gload16(bp + (size_t)kc * 4096, Bd + w * 1024);
    gload16(bp + (size_t)kc * 4096 + 512, Bd + w * 1024 + 512);
    if (kc < 8) {
      // x-half: reg-stage from gathered fp32, convert, swizzled ds_write
      const float* s0 = xp0 + kc * 32;
      const float* s1 = xp1 + kc * 32;
      float4 a0 = *(const float4*)(s0);
      float4 a1 = *(const float4*)(s0 + 16);
      float4 b0 = *(const float4*)(s1);
      float4 b1 = *(const float4*)(s1 + 16);
      uint4 u0 = make_uint4(pkbf2(a0.x, a0.y), pkbf2(a0.z, a0.w),
                            pkbf2(a1.x, a1.y), pkbf2(a1.z, a1.w));
      uint4 u1 = make_uint4(pkbf2(b0.x, b0.y), pkbf2(b0.z, b0.w),
                            pkbf2(b1.x, b1.y), pkbf2(b1.z, b1.w));
      *(uint4*)(Ad + r0 * 32 + wrX) = u0;
      *(uint4*)(Ad + (r0 + 16) * 32 + wrX) = u1;
    } else {
      // h-half: direct global_load_lds from permuted bf16 h
      gload16(hp0 + (kc - 8) * 32, Ad + w * 1024);
      gload16(hp1 + (kc - 8) * 32, Ad + w * 1024 + 512);
    }
  };

  const int lr = l & 15;
  const int lq = l >> 4;
  const int slot_r = (lq ^ ((l >> 1) & 3)) * 8;  // swizzled read slot (shorts)

  auto COMPUTE = [&](int buf) {
    short8 af[4], bf[4];
#pragma unroll
    for (int mi = 0; mi < 4; ++mi)
      af[mi] = *(const short8*)&As[buf][(wm * 64 + mi * 16 + lr) * 32 + slot_r];
#pragma unroll
    for (int ni = 0; ni < 4; ++ni)
      bf[ni] = *(const short8*)&Bs[buf][(wn * 64 + ni * 16 + lr) * 32 + slot_r];
#pragma unroll
    for (int mi = 0; mi < 4; ++mi)
#pragma unroll
      for (int ni = 0; ni < 4; ++ni)
        acc[mi][ni] = __builtin_amdgcn_mfma_f32_16x16x32_bf16(af[mi], bf[ni], acc[mi][ni], 0, 0, 0);
  };

  const int NK = first ? 8 : 16;
  STAGE(0, 0);
  __syncthreads();
  for (int kc = 0; kc < NK; ++kc) {
    const int cur = kc & 1;
    if (kc + 1 < NK) STAGE(cur ^ 1, kc + 1);
    COMPUTE(cur);
    __syncthreads();
  }

  // ---- epilogue: gates -> c,h ----
  const int hc = tn * 32 + wn * 16 + lr;
  const float bi = bcat[hc], bff = bcat[256 + hc], bg = bcat[512 + hc], bo = bcat[768 + hc];
  const int kl = hc & 31;
  const int hpos = (hc & ~31) + ((kl >> 2) & 3) * 8 + ((kl >> 4) & 1) * 4 + (kl & 3);
#pragma unroll
  for (int mi = 0; mi < 4; ++mi) {
#pragma unroll
    for (int r = 0; r < 4; ++r) {
      const int m = m0 + wm * 64 + mi * 16 + lq * 4 + r;
      const size_t off = (size_t)m * 256;
      const float zi = acc[mi][0][r] + bi;
      const float zf = acc[mi][1][r] + bff;
      const float zg = acc[mi][2][r] + bg;
      const float zo = acc[mi][3][r] + bo;
      const float cp = first ? 0.f : cbuf[off + hc];
      const float cn = sigf(zf) * cp + sigf(zi) * tanh_fast(zg);
      const float hn = sigf(zo) * tanh_fast(cn);
      cbuf[off + hc] = cn;
      hb_out[off + hpos] = bf16r(hn);
      if (hf32) hf32[off + hc] = hn;
    }
  }
}

// ---------------- fp32 combine GEMM: out = act([src1|src2] @ W^T + bias) ----------------
__global__ __launch_bounds__(256) void gemm_combine_kernel(
    const float* __restrict__ src1, const float* src2,
    const float* __restrict__ W, const float* __restrict__ bias,
    float* __restrict__ out, int Ktot, int do_gelu)
{
  __shared__ float Xs[64][36];
  __shared__ float Ws[32][64];

  const int tid = threadIdx.x;
  const int m0 = blockIdx.x * 64;
  const int hc0 = blockIdx.y * 64;
  const int ty = tid >> 4, tx = tid & 15;
  const int r0 = ty * 4, c0 = tx * 4;

  float acc[4][4];
#pragma unroll
  for (int i = 0; i < 4; ++i)
#pragma unroll
    for (int j = 0; j < 4; ++j) acc[i][j] = 0.f;

  const int lr = tid >> 2;
  const int lk = (tid & 3) * 8;
  const float* xrowA = src1 + (size_t)(m0 + lr) * 256;
  const float* xrowB = src2 ? src2 + (size_t)(m0 + lr) * 256 : nullptr;

  const int wn = tid >> 2;
  const int wk = (tid & 3) * 8;
  const float* wrow = W + (size_t)(hc0 + wn) * Ktot;

  const int nchunk = Ktot / 32;
  for (int kc = 0; kc < nchunk; ++kc) {
    const int k0 = kc * 32;
    __syncthreads();
    {
      const float* src = (k0 < 256) ? (xrowA + k0 + lk) : (xrowB + (k0 - 256) + lk);
      float4 a = ((const float4*)src)[0];
      float4 b = ((const float4*)src)[1];
      *(float4*)&Xs[lr][lk] = a;
      *(float4*)&Xs[lr][lk + 4] = b;
    }
    {
#pragma unroll
      for (int u = 0; u < 2; ++u) {
        float4 wv = *(const float4*)(wrow + k0 + wk + u * 4);
        Ws[wk + u * 4 + 0][wn] = wv.x;
        Ws[wk + u * 4 + 1][wn] = wv.y;
        Ws[wk + u * 4 + 2][wn] = wv.z;
        Ws[wk + u * 4 + 3][wn] = wv.w;
      }
    }
    __syncthreads();
#pragma unroll 4
    for (int k = 0; k < 32; ++k) {
      float x0 = Xs[r0 + 0][k], x1 = Xs[r0 + 1][k];
      float x2 = Xs[r0 + 2][k], x3 = Xs[r0 + 3][k];
      float4 wv = *(const float4*)&Ws[k][c0];
      acc[0][0] += x0 * wv.x; acc[0][1] += x0 * wv.y; acc[0][2] += x0 * wv.z; acc[0][3] += x0 * wv.w;
      acc[1][0] += x1 * wv.x; acc[1][1] += x1 * wv.y; acc[1][2] += x1 * wv.z; acc[1][3] += x1 * wv.w;
      acc[2][0] += x2 * wv.x; acc[2][1] += x2 * wv.y; acc[2][2] += x2 * wv.z; acc[2][3] += x2 * wv.w;
      acc[3][0] += x3 * wv.x; acc[3][1] += x3 * wv.y; acc[3][2] += x3 * wv.z; acc[3][3] += x3 * wv.w;
    }
  }

#pragma unroll
  for (int i = 0; i < 4; ++i) {
    const int m = m0 + r0 + i;
    float o[4];
#pragma unroll
    for (int j = 0; j < 4; ++j) {
      float v = acc[i][j] + bias[hc0 + c0 + j];
      if (do_gelu) v = 0.5f * v * (1.f + erff(v * 0.70710678118654752f));
      o[j] = v;
    }
    *(float4*)&out[(size_t)m * 256 + hc0 + c0] = make_float4(o[0], o[1], o[2], o[3]);
  }
}

// ---------------- layernorm (+ optional batchnorm) ----------------
__global__ __launch_bounds__(256) void ln_bn_kernel(
    const float* __restrict__ in, float* __restrict__ out,
    const float* __restrict__ g, const float* __restrict__ b,
    const float* bnm, const float* bnv, const float* bng, const float* bnb,
    int do_bn)
{
  const int row = blockIdx.x * 4 + (threadIdx.x >> 6);
  const int lane = threadIdx.x & 63;
  const int c = lane * 4;
  float4 v = *(const float4*)(in + (size_t)row * 256 + c);
  float s = v.x + v.y + v.z + v.w;
  float qq = v.x * v.x + v.y * v.y + v.z * v.z + v.w * v.w;
#pragma unroll
  for (int o = 32; o > 0; o >>= 1) { s += __shfl_xor(s, o); qq += __shfl_xor(qq, o); }
  const float mu = s * (1.f / 256.f);
  const float var = qq * (1.f / 256.f) - mu * mu;
  const float rs = rsqrtf(var + 1e-5f);
  float vv[4] = { v.x, v.y, v.z, v.w };
  float y[4];
#pragma unroll
  for (int j = 0; j < 4; ++j) {
    float t = (vv[j] - mu) * rs * g[c + j] + b[c + j];
    if (do_bn) t = (t - bnm[c + j]) * rsqrtf(bnv[c + j] + 1e-5f) * bng[c + j] + bnb[c + j];
    y[j] = t;
  }
  *(float4*)(out + (size_t)row * 256 + c) = make_float4(y[0], y[1], y[2], y[3]);
}

__global__ __launch_bounds__(256) void head_kernel(
    const float* __restrict__ h4, const float* __restrict__ W2,
    const float* __restrict__ b2, float* __restrict__ out)
{
  const int row = blockIdx.x * 4 + (threadIdx.x >> 6);
  const int lane = threadIdx.x & 63;
  float4 a = *(const float4*)(h4 + (size_t)row * 256 + lane * 4);
  float4 w = *(const float4*)(W2 + lane * 4);
  float s = a.x * w.x + a.y * w.y + a.z * w.z + a.w * w.w;
#pragma unroll
  for (int o = 32; o > 0; o >>= 1) s += __shfl_xor(s, o);
  if (lane == 0) out[row] = s + b2[0];
}

// ---------------- launch ----------------
extern "C" void kernel_launch(void* const* d_in, const int* in_sizes, int n_in,
                              void* d_out, int out_size, void* d_ws, size_t ws_size,
                              hipStream_t stream) {
  const float* h0       = (const float*)d_in[0];
  const int*   idx0     = (const int*)  d_in[1];
  const int*   idx1     = (const int*)  d_in[2];
  const float* W_ih1    = (const float*)d_in[3];
  const float* W_hh1    = (const float*)d_in[4];
  const float* b_ih1    = (const float*)d_in[5];
  const float* b_hh1    = (const float*)d_in[6];
  const float* W_self1  = (const float*)d_in[7];
  const float* W_neigh1 = (const float*)d_in[8];
  const float* b_neigh1 = (const float*)d_in[9];
  const float* W_ih2    = (const float*)d_in[10];
  const float* W_hh2    = (const float*)d_in[11];
  const float* b_ih2    = (const float*)d_in[12];
  const float* b_hh2    = (const float*)d_in[13];
  const float* W_self2  = (const float*)d_in[14];
  const float* W_neigh2 = (const float*)d_in[15];
  const float* b_neigh2 = (const float*)d_in[16];
  const float* ln_g     = (const float*)d_in[17];
  const float* ln_b     = (const float*)d_in[18];
  const float* bn_g     = (const float*)d_in[19];
  const float* bn_b     = (const float*)d_in[20];
  const float* bn_mean  = (const float*)d_in[21];
  const float* bn_var   = (const float*)d_in[22];
  const float* W1       = (const float*)d_in[23];
  const float* b1       = (const float*)d_in[24];
  const float* W2       = (const float*)d_in[25];
  const float* b2       = (const float*)d_in[26];
  float* out = (float*)d_out;

  // ---- workspace layout (float units) ----
  float* ws = (float*)d_ws;
  unsigned short* packB1 = (unsigned short*)ws;                 // 524288 shorts = 262144 f
  unsigned short* packB2 = (unsigned short*)(ws + 262144);      // 262144 f
  float* Wcmb1 = ws + 524288;        // 131072
  float* Wcmb2 = Wcmb1 + 131072;     // 131072
  float* bcat1 = Wcmb2 + 131072;     // 1024
  float* bcat2 = bcat1 + 1024;       // 1024
  unsigned short* hbA = (unsigned short*)(bcat2 + 1024);        // 16384*256 shorts = 2097152 f
  unsigned short* hbB = (unsigned short*)(bcat2 + 1024 + 2097152);
  float* cbuf = bcat2 + 1024 + 4194304;   // 4194304
  float* hf32 = cbuf + 4194304;           // 4194304
  float* h1   = hf32 + 4194304;           // 4194304
  float* sbuf = h1 + 4194304;             // 4194304
  float* h3   = sbuf + 4194304;           // 1048576
  float* h4   = h3 + 1048576;             // 1048576

  // ---- prep ----
  pack_w_kernel<<<2048, 256, 0, stream>>>(packB1, W_ih1, W_hh1);
  pack_w_kernel<<<2048, 256, 0, stream>>>(packB2, W_ih2, W_hh2);
  concat_rows_kernel<<<128, 256, 0, stream>>>(Wcmb1, W_self1, W_neigh1, 256);
  concat_rows_kernel<<<128, 256, 0, stream>>>(Wcmb2, W_self2, W_neigh2, 256);
  add_bias_kernel<<<4, 256, 0, stream>>>(bcat1, b_ih1, b_hh1, 1024);
  add_bias_kernel<<<4, 256, 0, stream>>>(bcat2, b_ih2, b_hh2, 1024);

  // ---- layer 1 LSTM ----
  for (int t = 0; t < PK; ++t) {
    unsigned short* hin  = (t & 1) ? hbA : hbB;   // unused when t==0
    unsigned short* hout = (t & 1) ? hbB : hbA;
    lstm_mfma_kernel<<<dim3(PN1 / 128, 8), 256, 0, stream>>>(
        h0, idx0, t, hin, packB1, bcat1, cbuf, hout,
        (t == PK - 1) ? hf32 : nullptr, t == 0);
  }
  gemm_combine_kernel<<<dim3(PN1 / 64, 4), 256, 0, stream>>>(h0, hf32, Wcmb1, b_neigh1,
                                                             sbuf, 512, 1);
  ln_bn_kernel<<<PN1 / 4, 256, 0, stream>>>(sbuf, h1, ln_g, ln_b,
                                            nullptr, nullptr, nullptr, nullptr, 0);

  // ---- layer 2 LSTM ----
  for (int t = 0; t < PK; ++t) {
    unsigned short* hin  = (t & 1) ? hbA : hbB;
    unsigned short* hout = (t & 1) ? hbB : hbA;
    lstm_mfma_kernel<<<dim3(PN2 / 128, 8), 256, 0, stream>>>(
        h1, idx1, t, hin, packB2, bcat2, cbuf, hout,
        (t == PK - 1) ? hf32 : nullptr, t == 0);
  }
  gemm_combine_kernel<<<dim3(PN2 / 64, 4), 256, 0, stream>>>(h1, hf32, Wcmb2, b_neigh2,
                                                             sbuf, 512, 1);
  ln_bn_kernel<<<PN2 / 4, 256, 0, stream>>>(sbuf, h3, ln_g, ln_b,
                                            bn_mean, bn_var, bn_g, bn_b, 1);
  gemm_combine_kernel<<<dim3(PN2 / 64, 4), 256, 0, stream>>>(h3, nullptr, W1, b1,
                                                             h4, 256, 1);
  head_kernel<<<PN2 / 4, 256, 0, stream>>>(h4, W2, b2, out);
}

// Round 3
// 532.925 us; speedup vs baseline: 4.6085x; 1.2309x over previous
//
#include <hip/hip_runtime.h>
#include <hip/hip_bf16.h>
#include <math.h>

#define PN0 131072
#define PN1 16384
#define PN2 4096
#define PK  8

typedef __attribute__((ext_vector_type(8))) short short8;
typedef __attribute__((ext_vector_type(4))) float f32x4;

__device__ __forceinline__ unsigned pkbf2(float a, float b) {
  unsigned ua = __float_as_uint(a); ua = (ua + 0x7FFFu + ((ua >> 16) & 1u)) >> 16;
  unsigned ub = __float_as_uint(b); ub = (ub + 0x7FFFu + ((ub >> 16) & 1u)) >> 16;
  return ua | (ub << 16);
}
__device__ __forceinline__ unsigned short bf16r(float a) {
  unsigned ua = __float_as_uint(a);
  return (unsigned short)((ua + 0x7FFFu + ((ua >> 16) & 1u)) >> 16);
}
__device__ __forceinline__ float sigf(float x) { return 1.f / (1.f + __expf(-x)); }
__device__ __forceinline__ float tanh_fast(float x) { return 1.f - 2.f / (__expf(2.f * x) + 1.f); }

__device__ __forceinline__ void gload16(const void* g, void* l) {
  __builtin_amdgcn_global_load_lds(
      (const __attribute__((address_space(1))) void*)g,
      (__attribute__((address_space(3))) void*)l, 16, 0, 0);
}

// ---- fp32 rows -> bf16 k-permuted rows (stacked-4 per 32-k block) ----
// within 32: k = 16*e2 + 4*q + e1 stored at pos q*8 + e2*4 + e1
__global__ __launch_bounds__(256) void cvt_perm_kernel(
    unsigned short* __restrict__ dst, const float* __restrict__ src, int nrow) {
  int t = blockIdx.x * 256 + threadIdx.x;
  if (t >= nrow * 8) return;
  int row = t >> 3, c0 = (t & 7) * 32;
  const float* s = src + (size_t)row * 256 + c0;
  unsigned short* d = dst + (size_t)row * 256 + c0;
  float f[32];
#pragma unroll
  for (int i = 0; i < 8; ++i) *(float4*)&f[i * 4] = *(const float4*)(s + i * 4);
#pragma unroll
  for (int q = 0; q < 4; ++q) {
    uint4 u;
    u.x = pkbf2(f[4 * q + 0], f[4 * q + 1]);
    u.y = pkbf2(f[4 * q + 2], f[4 * q + 3]);
    u.z = pkbf2(f[16 + 4 * q + 0], f[16 + 4 * q + 1]);
    u.w = pkbf2(f[16 + 4 * q + 2], f[16 + 4 * q + 3]);
    *(uint4*)(d + q * 8) = u;
  }
}

// ---- gated weight pack: Wcat(1024x512) -> 8 tiles x 16 kc x 128 rows x 32 (swizzled) ----
__global__ __launch_bounds__(256) void pack_w_kernel(
    unsigned short* __restrict__ dst, const float* __restrict__ Wih,
    const float* __restrict__ Whh) {
  int t = blockIdx.x * 256 + threadIdx.x;      // 524288 total
  int e = t & 7, slot = (t >> 3) & 3, row = (t >> 5) & 127;
  int kc = (t >> 12) & 15, tn = t >> 16;
  int q = slot ^ ((row >> 1) & 3);
  int k = kc * 32 + 16 * (e >> 2) + 4 * q + (e & 3);
  int hc = tn * 32 + ((row >> 6) << 4) + (row & 15);
  int g = (row >> 4) & 3;
  int n = g * 256 + hc;
  float v = (k < 256) ? Wih[(size_t)n * 256 + k] : Whh[(size_t)n * 256 + (k - 256)];
  dst[t] = bf16r(v);
}

// ---- plain weight pack: W(256 x Ktot) -> tiles x nkc x 128 rows x 32 (swizzled); n = tn*128+row ----
__global__ __launch_bounds__(256) void pack_plain_kernel(
    unsigned short* __restrict__ dst, const float* __restrict__ A,
    const float* __restrict__ B, int nkc, int total) {
  int t = blockIdx.x * 256 + threadIdx.x;
  if (t >= total) return;
  int e = t & 7, slot = (t >> 3) & 3, row = (t >> 5) & 127;
  int rest = t >> 12;
  int kc = rest % nkc, tn = rest / nkc;
  int q = slot ^ ((row >> 1) & 3);
  int k = kc * 32 + 16 * (e >> 2) + 4 * q + (e & 3);
  int n = tn * 128 + row;
  float v = (k < 256) ? A[(size_t)n * 256 + k] : B[(size_t)n * 256 + (k - 256)];
  dst[t] = bf16r(v);
}

__global__ __launch_bounds__(256) void add_bias_kernel(
    float* __restrict__ dst, const float* __restrict__ a,
    const float* __restrict__ b, int n) {
  int i = blockIdx.x * 256 + threadIdx.x;
  if (i < n) dst[i] = a[i] + b[i];
}

// ---------------- MFMA LSTM step (all-bf16 staging via global_load_lds) ----------------
// grid (M/128, 8); block 256 (4 waves 2x2). Z = [x_t | h] @ packW; gates -> c,h.
__global__ __launch_bounds__(256) void lstm_mfma_kernel(
    const unsigned short* __restrict__ xb,     // bf16 permuted gather source
    const int* __restrict__ idx, int t,
    const unsigned short* __restrict__ hb_in,  // bf16 permuted h_prev
    const unsigned short* __restrict__ packW,
    const float* __restrict__ bcat,
    float* __restrict__ cbuf,
    unsigned short* __restrict__ hb_out,
    int first)
{
  __shared__ short As[2][4096];
  __shared__ short Bs[2][4096];

  const int tid = threadIdx.x;
  const int l = tid & 63;
  const int w = tid >> 6;
  const int m0 = blockIdx.x * 128;
  const int tn = blockIdx.y;
  const int wm = w >> 1, wn = w & 1;

  const int q = (l & 3) ^ ((l >> 3) & 3);
  const int r0 = w * 32 + (l >> 2);
  const int m_a = m0 + r0;
  const int m_b = m_a + 16;
  const unsigned short* xp0 = xb + (size_t)idx[(size_t)m_a * PK + t] * 256 + 8 * q;
  const unsigned short* xp1 = xb + (size_t)idx[(size_t)m_b * PK + t] * 256 + 8 * q;
  const unsigned short* hp0 = hb_in + (size_t)m_a * 256 + 8 * q;
  const unsigned short* hp1 = hb_in + (size_t)m_b * 256 + 8 * q;
  const unsigned short* bp = packW + (size_t)tn * 65536 + (size_t)w * 1024 + (size_t)l * 8;

  f32x4 acc[4][4];
#pragma unroll
  for (int mi = 0; mi < 4; ++mi)
#pragma unroll
    for (int ni = 0; ni < 4; ++ni) acc[mi][ni] = (f32x4)(0.f);

  auto STAGE = [&](int buf, int kc) {
    short* Ad = &As[buf][0];
    short* Bd = &Bs[buf][0];
    gload16(bp + (size_t)kc * 4096, Bd + w * 1024);
    gload16(bp + (size_t)kc * 4096 + 512, Bd + w * 1024 + 512);
    const unsigned short *s0, *s1;
    if (kc < 8) { s0 = xp0 + kc * 32; s1 = xp1 + kc * 32; }
    else        { s0 = hp0 + (kc - 8) * 32; s1 = hp1 + (kc - 8) * 32; }
    gload16(s0, Ad + w * 1024);
    gload16(s1, Ad + w * 1024 + 512);
  };

  const int lr = l & 15;
  const int lq = l >> 4;
  const int slot_r = (lq ^ ((l >> 1) & 3)) * 8;

  auto COMPUTE = [&](int buf) {
    short8 af[4], bf[4];
#pragma unroll
    for (int mi = 0; mi < 4; ++mi)
      af[mi] = *(const short8*)&As[buf][(wm * 64 + mi * 16 + lr) * 32 + slot_r];
#pragma unroll
    for (int ni = 0; ni < 4; ++ni)
      bf[ni] = *(const short8*)&Bs[buf][(wn * 64 + ni * 16 + lr) * 32 + slot_r];
#pragma unroll
    for (int mi = 0; mi < 4; ++mi)
#pragma unroll
      for (int ni = 0; ni < 4; ++ni)
        acc[mi][ni] = __builtin_amdgcn_mfma_f32_16x16x32_bf16(af[mi], bf[ni], acc[mi][ni], 0, 0, 0);
  };

  const int NK = first ? 8 : 16;
  STAGE(0, 0);
  __syncthreads();
  for (int kc = 0; kc < NK; ++kc) {
    const int cur = kc & 1;
    if (kc + 1 < NK) STAGE(cur ^ 1, kc + 1);
    COMPUTE(cur);
    __syncthreads();
  }

  // epilogue: gates -> c,h
  const int hc = tn * 32 + wn * 16 + lr;
  const float bi = bcat[hc], bff = bcat[256 + hc], bg = bcat[512 + hc], bo = bcat[768 + hc];
  const int kl = hc & 31;
  const int hpos = (hc & ~31) + ((kl >> 2) & 3) * 8 + ((kl >> 4) & 1) * 4 + (kl & 3);
#pragma unroll
  for (int mi = 0; mi < 4; ++mi) {
#pragma unroll
    for (int r = 0; r < 4; ++r) {
      const int m = m0 + wm * 64 + mi * 16 + lq * 4 + r;
      const size_t off = (size_t)m * 256;
      const float zi = acc[mi][0][r] + bi;
      const float zf = acc[mi][1][r] + bff;
      const float zg = acc[mi][2][r] + bg;
      const float zo = acc[mi][3][r] + bo;
      const float cp = first ? 0.f : cbuf[off + hc];
      const float cn = sigf(zf) * cp + sigf(zi) * tanh_fast(zg);
      const float hn = sigf(zo) * tanh_fast(cn);
      cbuf[off + hc] = cn;
      hb_out[off + hpos] = bf16r(hn);
    }
  }
}

// ---------------- generic MFMA GEMM: out = act([selfb | neighb] @ packW + bias), fp32 out ----------------
// grid (M/128, Ntiles); NK = Ktot/32 (16 or 8). out width = Ntiles*128 (=256 here).
__global__ __launch_bounds__(256) void gemm_bf16_kernel(
    const unsigned short* __restrict__ selfb,
    const unsigned short* __restrict__ neighb,   // may be null when NK==8
    const unsigned short* __restrict__ packW,
    const float* __restrict__ bias,
    float* __restrict__ out, int NK, int do_gelu)
{
  __shared__ short As[2][4096];
  __shared__ short Bs[2][4096];

  const int tid = threadIdx.x;
  const int l = tid & 63;
  const int w = tid >> 6;
  const int m0 = blockIdx.x * 128;
  const int tn = blockIdx.y;
  const int wm = w >> 1, wn = w & 1;

  const int q = (l & 3) ^ ((l >> 3) & 3);
  const int r0 = w * 32 + (l >> 2);
  const int m_a = m0 + r0;
  const int m_b = m_a + 16;
  const unsigned short* sp0 = selfb + (size_t)m_a * 256 + 8 * q;
  const unsigned short* sp1 = selfb + (size_t)m_b * 256 + 8 * q;
  const unsigned short* np0 = neighb ? neighb + (size_t)m_a * 256 + 8 * q : sp0;
  const unsigned short* np1 = neighb ? neighb + (size_t)m_b * 256 + 8 * q : sp1;
  const unsigned short* bp = packW + (size_t)tn * 4096 * NK + (size_t)w * 1024 + (size_t)l * 8;

  f32x4 acc[4][4];
#pragma unroll
  for (int mi = 0; mi < 4; ++mi)
#pragma unroll
    for (int ni = 0; ni < 4; ++ni) acc[mi][ni] = (f32x4)(0.f);

  auto STAGE = [&](int buf, int kc) {
    short* Ad = &As[buf][0];
    short* Bd = &Bs[buf][0];
    gload16(bp + (size_t)kc * 4096, Bd + w * 1024);
    gload16(bp + (size_t)kc * 4096 + 512, Bd + w * 1024 + 512);
    const unsigned short *s0, *s1;
    if (kc < 8) { s0 = sp0 + kc * 32; s1 = sp1 + kc * 32; }
    else        { s0 = np0 + (kc - 8) * 32; s1 = np1 + (kc - 8) * 32; }
    gload16(s0, Ad + w * 1024);
    gload16(s1, Ad + w * 1024 + 512);
  };

  const int lr = l & 15;
  const int lq = l >> 4;
  const int slot_r = (lq ^ ((l >> 1) & 3)) * 8;

  auto COMPUTE = [&](int buf) {
    short8 af[4], bf[4];
#pragma unroll
    for (int mi = 0; mi < 4; ++mi)
      af[mi] = *(const short8*)&As[buf][(wm * 64 + mi * 16 + lr) * 32 + slot_r];
#pragma unroll
    for (int ni = 0; ni < 4; ++ni)
      bf[ni] = *(const short8*)&Bs[buf][(wn * 64 + ni * 16 + lr) * 32 + slot_r];
#pragma unroll
    for (int mi = 0; mi < 4; ++mi)
#pragma unroll
      for (int ni = 0; ni < 4; ++ni)
        acc[mi][ni] = __builtin_amdgcn_mfma_f32_16x16x32_bf16(af[mi], bf[ni], acc[mi][ni], 0, 0, 0);
  };

  STAGE(0, 0);
  __syncthreads();
  for (int kc = 0; kc < NK; ++kc) {
    const int cur = kc & 1;
    if (kc + 1 < NK) STAGE(cur ^ 1, kc + 1);
    COMPUTE(cur);
    __syncthreads();
  }

#pragma unroll
  for (int mi = 0; mi < 4; ++mi) {
#pragma unroll
    for (int ni = 0; ni < 4; ++ni) {
      const int n = tn * 128 + wn * 64 + ni * 16 + lr;
      const float bb = bias[n];
#pragma unroll
      for (int r = 0; r < 4; ++r) {
        const int m = m0 + wm * 64 + mi * 16 + lq * 4 + r;
        float v = acc[mi][ni][r] + bb;
        if (do_gelu) v = 0.5f * v * (1.f + erff(v * 0.70710678118654752f));
        out[(size_t)m * 256 + n] = v;
      }
    }
  }
}

// ---------------- layernorm (+ optional batchnorm), fp32 in -> bf16 permuted out ----------------
__global__ __launch_bounds__(256) void ln_bn_kernel(
    const float* __restrict__ in, unsigned short* __restrict__ outb,
    const float* __restrict__ g, const float* __restrict__ b,
    const float* bnm, const float* bnv, const float* bng, const float* bnb,
    int do_bn)
{
  const int row = blockIdx.x * 4 + (threadIdx.x >> 6);
  const int lane = threadIdx.x & 63;
  const int c = lane * 4;
  float4 v = *(const float4*)(in + (size_t)row * 256 + c);
  float s = v.x + v.y + v.z + v.w;
  float qq = v.x * v.x + v.y * v.y + v.z * v.z + v.w * v.w;
#pragma unroll
  for (int o = 32; o > 0; o >>= 1) { s += __shfl_xor(s, o); qq += __shfl_xor(qq, o); }
  const float mu = s * (1.f / 256.f);
  const float var = qq * (1.f / 256.f) - mu * mu;
  const float rs = rsqrtf(var + 1e-5f);
  float vv[4] = { v.x, v.y, v.z, v.w };
  float y[4];
#pragma unroll
  for (int j = 0; j < 4; ++j) {
    float t = (vv[j] - mu) * rs * g[c + j] + b[c + j];
    if (do_bn) t = (t - bnm[c + j]) * rsqrtf(bnv[c + j] + 1e-5f) * bng[c + j] + bnb[c + j];
    y[j] = t;
  }
  // permuted bf16 write: 4 consecutive k share (q,e2)
  const int base = (c & ~31) + (((c >> 2) & 3) * 8) + (((c >> 4) & 1) * 4);
  uint2 u = make_uint2(pkbf2(y[0], y[1]), pkbf2(y[2], y[3]));
  *(uint2*)(outb + (size_t)row * 256 + base) = u;
}

__global__ __launch_bounds__(256) void head_kernel(
    const float* __restrict__ h4, const float* __restrict__ W2,
    const float* __restrict__ b2, float* __restrict__ out)
{
  const int row = blockIdx.x * 4 + (threadIdx.x >> 6);
  const int lane = threadIdx.x & 63;
  float4 a = *(const float4*)(h4 + (size_t)row * 256 + lane * 4);
  float4 w = *(const float4*)(W2 + lane * 4);
  float s = a.x * w.x + a.y * w.y + a.z * w.z + a.w * w.w;
#pragma unroll
  for (int o = 32; o > 0; o >>= 1) s += __shfl_xor(s, o);
  if (lane == 0) out[row] = s + b2[0];
}

// ---------------- launch ----------------
extern "C" void kernel_launch(void* const* d_in, const int* in_sizes, int n_in,
                              void* d_out, int out_size, void* d_ws, size_t ws_size,
                              hipStream_t stream) {
  const float* h0       = (const float*)d_in[0];
  const int*   idx0     = (const int*)  d_in[1];
  const int*   idx1     = (const int*)  d_in[2];
  const float* W_ih1    = (const float*)d_in[3];
  const float* W_hh1    = (const float*)d_in[4];
  const float* b_ih1    = (const float*)d_in[5];
  const float* b_hh1    = (const float*)d_in[6];
  const float* W_self1  = (const float*)d_in[7];
  const float* W_neigh1 = (const float*)d_in[8];
  const float* b_neigh1 = (const float*)d_in[9];
  const float* W_ih2    = (const float*)d_in[10];
  const float* W_hh2    = (const float*)d_in[11];
  const float* b_ih2    = (const float*)d_in[12];
  const float* b_hh2    = (const float*)d_in[13];
  const float* W_self2  = (const float*)d_in[14];
  const float* W_neigh2 = (const float*)d_in[15];
  const float* b_neigh2 = (const float*)d_in[16];
  const float* ln_g     = (const float*)d_in[17];
  const float* ln_b     = (const float*)d_in[18];
  const float* bn_g     = (const float*)d_in[19];
  const float* bn_b     = (const float*)d_in[20];
  const float* bn_mean  = (const float*)d_in[21];
  const float* bn_var   = (const float*)d_in[22];
  const float* W1       = (const float*)d_in[23];
  const float* b1       = (const float*)d_in[24];
  const float* W2       = (const float*)d_in[25];
  const float* b2       = (const float*)d_in[26];
  float* out = (float*)d_out;

  // ---- workspace layout (float units) ----
  float* ws = (float*)d_ws;
  unsigned short* packB1 = (unsigned short*)ws;                   // 524288 sh = 262144 f
  unsigned short* packB2 = (unsigned short*)(ws + 262144);        // 262144 f
  unsigned short* packC1 = (unsigned short*)(ws + 524288);        // 131072 sh = 65536 f
  unsigned short* packC2 = (unsigned short*)(ws + 589824);        // 65536 f
  unsigned short* packM  = (unsigned short*)(ws + 655360);        // 65536 sh = 32768 f
  float* bcat1 = ws + 688128;                                     // 1024
  float* bcat2 = bcat1 + 1024;                                    // 1024
  unsigned short* h0b = (unsigned short*)(bcat2 + 1024);          // 33554432 sh = 16777216 f
  unsigned short* hbA = (unsigned short*)(bcat2 + 1024 + 16777216); // 2097152 f
  unsigned short* hbB = (unsigned short*)(bcat2 + 1024 + 18874368); // 2097152 f
  float* cbuf = bcat2 + 1024 + 20971520;   // 4194304
  float* sbuf = cbuf + 4194304;            // 4194304
  unsigned short* h1b = (unsigned short*)(sbuf + 4194304);        // 2097152 f
  unsigned short* h3b = (unsigned short*)(sbuf + 4194304 + 2097152); // 524288 f
  float* h4 = sbuf + 4194304 + 2621440;    // 1048576

  // ---- prep ----
  cvt_perm_kernel<<<4096, 256, 0, stream>>>(h0b, h0, PN0);
  pack_w_kernel<<<2048, 256, 0, stream>>>(packB1, W_ih1, W_hh1);
  pack_w_kernel<<<2048, 256, 0, stream>>>(packB2, W_ih2, W_hh2);
  pack_plain_kernel<<<512, 256, 0, stream>>>(packC1, W_self1, W_neigh1, 16, 131072);
  pack_plain_kernel<<<512, 256, 0, stream>>>(packC2, W_self2, W_neigh2, 16, 131072);
  pack_plain_kernel<<<256, 256, 0, stream>>>(packM, W1, W1, 8, 65536);
  add_bias_kernel<<<4, 256, 0, stream>>>(bcat1, b_ih1, b_hh1, 1024);
  add_bias_kernel<<<4, 256, 0, stream>>>(bcat2, b_ih2, b_hh2, 1024);

  // ---- layer 1 LSTM ----
  for (int t = 0; t < PK; ++t) {
    unsigned short* hin  = (t & 1) ? hbA : hbB;
    unsigned short* hout = (t & 1) ? hbB : hbA;
    lstm_mfma_kernel<<<dim3(PN1 / 128, 8), 256, 0, stream>>>(
        h0b, idx0, t, hin, packB1, bcat1, cbuf, hout, t == 0);
  }
  // final h = hbB (t=7 odd)
  gemm_bf16_kernel<<<dim3(PN1 / 128, 2), 256, 0, stream>>>(h0b, hbB, packC1, b_neigh1,
                                                           sbuf, 16, 1);
  ln_bn_kernel<<<PN1 / 4, 256, 0, stream>>>(sbuf, h1b, ln_g, ln_b,
                                            nullptr, nullptr, nullptr, nullptr, 0);

  // ---- layer 2 LSTM ----
  for (int t = 0; t < PK; ++t) {
    unsigned short* hin  = (t & 1) ? hbA : hbB;
    unsigned short* hout = (t & 1) ? hbB : hbA;
    lstm_mfma_kernel<<<dim3(PN2 / 128, 8), 256, 0, stream>>>(
        h1b, idx1, t, hin, packB2, bcat2, cbuf, hout, t == 0);
  }
  gemm_bf16_kernel<<<dim3(PN2 / 128, 2), 256, 0, stream>>>(h1b, hbB, packC2, b_neigh2,
                                                           sbuf, 16, 1);
  ln_bn_kernel<<<PN2 / 4, 256, 0, stream>>>(sbuf, h3b, ln_g, ln_b,
                                            bn_mean, bn_var, bn_g, bn_b, 1);
  gemm_bf16_kernel<<<dim3(PN2 / 128, 2), 256, 0, stream>>>(h3b, nullptr, packM, b1,
                                                           h4, 8, 1);
  head_kernel<<<PN2 / 4, 256, 0, stream>>>(h4, W2, b2, out);
}